// Round 6
// baseline (249.172 us; speedup 1.0000x reference)
//
#include <hip/hip_runtime.h>
#include <hip/hip_bf16.h>

// B=8, S=4096, E=512, QKV=512, H=8, D=64, M=B*S=32768
// R9 pipeline (4 launches):
//   prep:      x fp32 -> bf16 + W transposes -> wt + zero ksg/kvg
//   gemm_qkv:  q = act(x@Wq+b) row-major; k,v stored ONLY TRANSPOSED
//              kT/vT[bh][d|m][4096] bf16 (k act'd), XCD-swizzled grid.
//              k-blocks also atomically accumulate ksum (fp32) into ksg[b][gcol].
//   kv:        MFMA GEMM over s (sc=8 x 512), 2-phase dbuf staging with counted
//              vmcnt(4) + raw s_barrier (no full drain); epilogue atomicAdd
//              fp32 into kvg[bh][m][d] (replaces kvp+mid).
//   fused_out: per 128x256 out block (2 ntiles): loop h { z from sQ x ksg,
//              sKV staged from kvg via reg-cvt path, o1_h = z*(q_h@kv_h^T) in
//              LDS, accumulate o1_h @ Wo_h } + bias -> out fp32 (XCD-swizzled)
// Scratch:
//   d_out[0,32M):  vT (dead after kv), then final out rows
//   d_out[32,64M): xb (dead after gemm_qkv) -> final out rows
//   ws: qb[0,32M) kT[32,64M) wt[64,66M) kvg[66,67M) ksg

typedef __bf16 bf16x8 __attribute__((ext_vector_type(8)));
typedef float  f32x4  __attribute__((ext_vector_type(4)));

__device__ __forceinline__ float b2f(unsigned short u) {
    unsigned int x = ((unsigned int)u) << 16;
    return __builtin_bit_cast(float, x);
}
__device__ __forceinline__ unsigned short f2b(float f) {
    unsigned int u = __builtin_bit_cast(unsigned int, f);
    unsigned int r = (u + 0x7FFFu + ((u >> 16) & 1u)) >> 16;
    return (unsigned short)r;
}
__device__ __forceinline__ void load_lds16(const unsigned short* g, unsigned short* l) {
    __builtin_amdgcn_global_load_lds(
        (const __attribute__((address_space(1))) void*)g,
        (__attribute__((address_space(3))) void*)l, 16, 0, 0);
}

// ---------------- prep: W transpose (blocks 0..255) + x cvt (blocks 256..) ---
__global__ void prep_kernel(const float* __restrict__ x,
                            const float* __restrict__ w0, const float* __restrict__ w1,
                            const float* __restrict__ w2, const float* __restrict__ w3,
                            unsigned short* __restrict__ xb, unsigned short* __restrict__ wt,
                            float* __restrict__ ksg, float* __restrict__ kvg) {
    __shared__ float tile[64][65];
    int t = threadIdx.x;
    if (blockIdx.x >= 256) {
        int i = (blockIdx.x - 256) * 256 + t;   // < 4194304
        float4 v = ((const float4*)x)[i];
        ushort4 o;
        o.x = f2b(v.x); o.y = f2b(v.y); o.z = f2b(v.z); o.w = f2b(v.w);
        ((ushort4*)xb)[i] = o;
        return;
    }
    int idx = blockIdx.x;
    if (idx < 16) ksg[idx * 256 + t] = 0.f;                 // zero ksum (4096 f32)
    ((float4*)kvg)[idx * 256 + t] = (float4){0.f, 0.f, 0.f, 0.f};  // zero kvg (1 MB)
    int bz = idx >> 6, by = (idx >> 3) & 7, bx = idx & 7;
    const float* src = (bz == 0) ? w0 : (bz == 1) ? w1 : (bz == 2) ? w2 : w3;
    unsigned short* dst = wt + (size_t)bz * 512 * 512;
    int rb = by * 64, cb = bx * 64;
    #pragma unroll
    for (int i = 0; i < 16; i++) {
        int c = t + i * 256; int r = c >> 6, cc = c & 63;
        tile[r][cc] = src[(rb + r) * 512 + cb + cc];
    }
    __syncthreads();
    #pragma unroll
    for (int i = 0; i < 16; i++) {
        int c = t + i * 256; int r = c >> 6, cc = c & 63;
        dst[(cb + r) * 512 + rb + cc] = f2b(tile[cc][r]);   // Wt[n][k]=W[k][n]
    }
}

// ---------------- gemm_qkv: 128x128 MFMA, q row-major / k,v transposed -------
// grid: 3072 1-D, XCD-swizzled: all 12 (tensor,ntile) blocks of one mtile get
// equal blockIdx%8 -> same XCD -> A-tile L2 hit.
// k-blocks (tensor==1) also accumulate fp32 column sums -> atomicAdd ksg.
__global__ __launch_bounds__(256, 4) void gemm_qkv_kernel(
        const unsigned short* __restrict__ xb, const unsigned short* __restrict__ wt,
        const float* __restrict__ bq, const float* __restrict__ bk, const float* __restrict__ bv,
        unsigned short* __restrict__ qb, unsigned short* __restrict__ kT,
        unsigned short* __restrict__ vT, float* __restrict__ ksg) {
    int g = blockIdx.x;
    int xcd = g & 7, slot = g >> 3;            // slot 0..383
    int mtile = xcd * 32 + slot / 12;
    int tn = slot % 12;
    int tensor = tn >> 2, ntile = tn & 3;
    const unsigned short* Bt = wt + (size_t)tensor * 512 * 512;
    const float* bias = tensor == 0 ? bq : tensor == 1 ? bk : bv;
    bool act = tensor < 2;

    __shared__ __align__(16) unsigned short sA[128 * 64];
    __shared__ __align__(16) unsigned short sB[128 * 64];
    const int tid  = threadIdx.x;
    const int wave = tid >> 6, lane = tid & 63;
    const int wm = wave >> 1, wn = wave & 1;
    const int quad = lane >> 4, l16 = lane & 15;
    const int mbase = mtile * 128, nbase = ntile * 128;
    const int rsub = lane >> 3;
    const int coff = (((lane & 7) ^ rsub) << 3);

    f32x4 acc[4][4];
    #pragma unroll
    for (int i = 0; i < 4; i++)
        #pragma unroll
        for (int j = 0; j < 4; j++) acc[i][j] = (f32x4){0.f, 0.f, 0.f, 0.f};

    for (int kb = 0; kb < 512; kb += 64) {
        #pragma unroll
        for (int t = 0; t < 4; t++) {
            int r0 = t * 32 + wave * 8;
            load_lds16(&xb[(size_t)(mbase + r0 + rsub) * 512 + kb + coff], &sA[r0 * 64]);
            load_lds16(&Bt[(size_t)(nbase + r0 + rsub) * 512 + kb + coff], &sB[r0 * 64]);
        }
        __syncthreads();
        #pragma unroll
        for (int ko = 0; ko < 64; ko += 32) {
            bf16x8 af[4], bfr[4];
            int pg = ((quad + (ko >> 3)) ^ (l16 & 7)) << 3;
            #pragma unroll
            for (int f = 0; f < 4; f++)
                af[f] = *(const bf16x8*)&sA[(wm * 64 + f * 16 + l16) * 64 + pg];
            #pragma unroll
            for (int f = 0; f < 4; f++)
                bfr[f] = *(const bf16x8*)&sB[(wn * 64 + f * 16 + l16) * 64 + pg];
            #pragma unroll
            for (int i = 0; i < 4; i++)
                #pragma unroll
                for (int j = 0; j < 4; j++)
                    acc[i][j] = __builtin_amdgcn_mfma_f32_16x16x32_bf16(af[i], bfr[j], acc[i][j], 0, 0, 0);
        }
        __syncthreads();
    }
    // epilogue. C/D layout: col = lane&15, row = quad*4+reg (m89-verified).
    if (tensor == 0) {
        #pragma unroll
        for (int i = 0; i < 4; i++)
            #pragma unroll
            for (int j = 0; j < 4; j++) {
                int gcol = nbase + wn * 64 + j * 16 + l16;
                float bv = bias[gcol];
                #pragma unroll
                for (int r = 0; r < 4; r++) {
                    int grow = mbase + wm * 64 + i * 16 + quad * 4 + r;
                    float v = acc[i][j][r] + bv;
                    v = v > 0.f ? v + 1.f : __expf(v);
                    qb[(size_t)grow * 512 + gcol] = f2b(v);
                }
            }
    } else {
        // transposed store: T[((b*8+h)*64 + d)*4096 + s], 4 consecutive s
        // (the 4 acc regs = rows quad*4+0..3) packed into one ushort4.
        unsigned short* T = (tensor == 1) ? kT : vT;
        float csum[4] = {0.f, 0.f, 0.f, 0.f};
        #pragma unroll
        for (int i = 0; i < 4; i++)
            #pragma unroll
            for (int j = 0; j < 4; j++) {
                int gcol = nbase + wn * 64 + j * 16 + l16;   // 0..511
                int h = gcol >> 6, d = gcol & 63;
                float bv = bias[gcol];
                int grow0 = mbase + wm * 64 + i * 16 + quad * 4;
                int b = grow0 >> 12, s0 = grow0 & 4095;
                ushort4 o;
                #pragma unroll
                for (int r = 0; r < 4; r++) {
                    float v = acc[i][j][r] + bv;
                    if (act) { v = v > 0.f ? v + 1.f : __expf(v); csum[j] += v; }
                    ((unsigned short*)&o)[r] = f2b(v);
                }
                *(ushort4*)&T[(((size_t)b * 8 + h) * 64 + d) * 4096 + s0] = o;
            }
        if (act) {   // tensor==1 (k): fp32 ksum accumulation, pre-bf16-rounding
            int b = mbase >> 12;
            #pragma unroll
            for (int j = 0; j < 4; j++) {
                float s = csum[j];
                s += __shfl_xor(s, 16, 64);   // quad reduce (rows quad*4+r)
                s += __shfl_xor(s, 32, 64);
                if (quad == 0) {
                    int gcol = nbase + wn * 64 + j * 16 + l16;
                    atomicAdd(&ksg[b * 512 + gcol], s);
                }
            }
        }
    }
}

// ---------------- kv: MFMA GEMM over s, 2-phase dbuf -------------------------
// grid: x = bh(64) * sc(8); block: C[64 m][64 d] partial over 512 s.
// Stage t+1 issued before compute t; counted vmcnt(4) + raw s_barrier (no
// full drain in-loop, T3/T4). Epilogue: fp32 atomicAdd into kvg[bh][m*64+d].
__global__ __launch_bounds__(256, 2) void kv_kernel(
        const unsigned short* __restrict__ kT, const unsigned short* __restrict__ vT,
        float* __restrict__ kvg) {
    int bh = blockIdx.x >> 3, sc = blockIdx.x & 7;
    const int tid = threadIdx.x;
    const int wave = tid >> 6, lane = tid & 63;
    const int wm = wave >> 1, wn = wave & 1;
    const int quad = lane >> 4, l16 = lane & 15;
    const int rsub = lane >> 3;
    const int coff = (((lane & 7) ^ rsub) << 3);
    __shared__ __align__(16) unsigned short sV[2][64 * 64];
    __shared__ __align__(16) unsigned short sK[2][64 * 64];

    f32x4 acc[2][2];
    #pragma unroll
    for (int i = 0; i < 2; i++)
        #pragma unroll
        for (int j = 0; j < 2; j++) acc[i][j] = (f32x4){0.f, 0.f, 0.f, 0.f};
    size_t base = (size_t)bh * 64 * 4096 + sc * 512;

    auto stage = [&](int kb, int buf) {
        int s0 = kb * 64;
        #pragma unroll
        for (int t = 0; t < 2; t++) {
            int r0 = t * 32 + wave * 8;
            load_lds16(&vT[base + (size_t)(r0 + rsub) * 4096 + s0 + coff], &sV[buf][r0 * 64]);
            load_lds16(&kT[base + (size_t)(r0 + rsub) * 4096 + s0 + coff], &sK[buf][r0 * 64]);
        }
    };

    stage(0, 0);                               // 4 loads in flight
    for (int kb = 0; kb < 8; kb++) {           // 8 x 64 s
        int buf = kb & 1;
        if (kb < 7) {
            stage(kb + 1, buf ^ 1);            // +4 -> 8 in flight
            asm volatile("s_waitcnt vmcnt(4)" ::: "memory");   // tile kb landed
        } else {
            asm volatile("s_waitcnt vmcnt(0)" ::: "memory");
        }
        __builtin_amdgcn_sched_barrier(0);
        __builtin_amdgcn_s_barrier();
        #pragma unroll
        for (int ko = 0; ko < 64; ko += 32) {
            bf16x8 af[2], bfr[2];
            int pg = ((quad + (ko >> 3)) ^ (l16 & 7)) << 3;
            #pragma unroll
            for (int f = 0; f < 2; f++)
                af[f] = *(const bf16x8*)&sV[buf][(wm * 32 + f * 16 + l16) * 64 + pg];
            #pragma unroll
            for (int f = 0; f < 2; f++)
                bfr[f] = *(const bf16x8*)&sK[buf][(wn * 32 + f * 16 + l16) * 64 + pg];
            #pragma unroll
            for (int i = 0; i < 2; i++)
                #pragma unroll
                for (int j = 0; j < 2; j++)
                    acc[i][j] = __builtin_amdgcn_mfma_f32_16x16x32_bf16(af[i], bfr[j], acc[i][j], 0, 0, 0);
        }
        __builtin_amdgcn_s_barrier();          // protect buf from next re-stage
        __builtin_amdgcn_sched_barrier(0);
    }
    // epilogue: accumulate fp32 partial into kvg (8 sc contenders per cell)
    float* out = kvg + (size_t)bh * 4096;
    #pragma unroll
    for (int i = 0; i < 2; i++)
        #pragma unroll
        for (int j = 0; j < 2; j++)
            #pragma unroll
            for (int r = 0; r < 4; r++) {
                int m = wm * 32 + i * 16 + quad * 4 + r;
                int d = wn * 32 + j * 16 + l16;
                atomicAdd(&out[m * 64 + d], acc[i][j][r]);
            }
}

// ---------------- fused out1 + output GEMM -----------------------------------
// grid: 512 1-D, XCD-swizzled (2 np blocks of one mtile -> same XCD).
// Each block: 128 rows x 256 cols (2 ntiles); o1/z/sQ computed ONCE per block.
// sKV staged from fp32 kvg via reg-cvt path (layout matches coff/pg reader).
__global__ __launch_bounds__(256, 2) void fused_out_kernel(
        const unsigned short* __restrict__ qb,
        const float* __restrict__ kvg, const float* __restrict__ ksg,
        const unsigned short* __restrict__ wto, const float* __restrict__ bo,
        float* __restrict__ out) {
    int g = blockIdx.x;
    int xcd = g & 7, slot = g >> 3;            // slot 0..63
    int mtile = xcd * 32 + (slot >> 1);
    int np = slot & 1;                         // col half: np*256 .. np*256+255

    __shared__ __align__(16) unsigned short sQ[128 * 64];
    __shared__ __align__(16) unsigned short sWo[2][128 * 64];
    __shared__ __align__(16) unsigned short sKV[64 * 64];
    __shared__ __align__(16) unsigned short sO1[128 * 64];
    __shared__ float sKsum[512];
    __shared__ float sZ[128];
    const int tid  = threadIdx.x;
    const int wave = tid >> 6, lane = tid & 63;
    const int wm = wave >> 1, wn = wave & 1;
    const int quad = lane >> 4, l16 = lane & 15;
    const int mbase = mtile * 128, nbase = np * 256;
    const int b = mtile >> 5;
    const int rsub = lane >> 3;
    const int coff = (((lane & 7) ^ rsub) << 3);

    // stage fp32 ksum for this b (512 cols = 8 h x 64 d)
    sKsum[tid]       = ksg[b * 512 + tid];
    sKsum[tid + 256] = ksg[b * 512 + 256 + tid];

    f32x4 accm[2][4][4];
    #pragma unroll
    for (int n = 0; n < 2; n++)
        #pragma unroll
        for (int i = 0; i < 4; i++)
            #pragma unroll
            for (int j = 0; j < 4; j++) accm[n][i][j] = (f32x4){0.f, 0.f, 0.f, 0.f};

    for (int h = 0; h < 8; h++) {
        #pragma unroll
        for (int t = 0; t < 4; t++) {
            int r0 = t * 32 + wave * 8;
            load_lds16(&qb[(size_t)(mbase + r0 + rsub) * 512 + h * 64 + coff], &sQ[r0 * 64]);
            load_lds16(&wto[(size_t)(nbase + r0 + rsub) * 512 + h * 64 + coff], &sWo[0][r0 * 64]);
            load_lds16(&wto[(size_t)(nbase + 128 + r0 + rsub) * 512 + h * 64 + coff], &sWo[1][r0 * 64]);
        }
        // sKV from fp32 kvg: thread handles 2 (row, G)-octets; swizzled 16B store
        #pragma unroll
        for (int oi = 0; oi < 2; oi++) {
            int idx = tid + oi * 256;          // 0..511: row = idx>>3, G = idx&7
            int row = idx >> 3, G = idx & 7;
            const float4* src = (const float4*)&kvg[((size_t)(b * 8 + h)) * 4096 + row * 64 + G * 8];
            float4 a = src[0], c = src[1];
            unsigned int p0 = (unsigned int)f2b(a.x) | ((unsigned int)f2b(a.y) << 16);
            unsigned int p1 = (unsigned int)f2b(a.z) | ((unsigned int)f2b(a.w) << 16);
            unsigned int p2 = (unsigned int)f2b(c.x) | ((unsigned int)f2b(c.y) << 16);
            unsigned int p3 = (unsigned int)f2b(c.z) | ((unsigned int)f2b(c.w) << 16);
            *(uint4*)&sKV[row * 64 + ((G ^ (row & 7)) << 3)] = (uint4){p0, p1, p2, p3};
        }
        __syncthreads();
        // z = 1/(q_h . ksum_h + eps) per row, from swizzled sQ (fp32 accum).
        {
            int row = tid >> 1, half = tid & 1;
            const float* ksh = &sKsum[h * 64];
            float dsum = 0.f;
            #pragma unroll
            for (int g2 = 0; g2 < 4; g2++) {
                int G = half * 4 + g2;                       // global octet
                uint4 w = *(const uint4*)&sQ[row * 64 + ((G ^ (row & 7)) << 3)];
                const unsigned int* qp = (const unsigned int*)&w;
                #pragma unroll
                for (int u = 0; u < 4; u++) {
                    int c = G * 8 + u * 2;
                    dsum += __builtin_bit_cast(float, qp[u] << 16)        * ksh[c];
                    dsum += __builtin_bit_cast(float, qp[u] & 0xFFFF0000u) * ksh[c + 1];
                }
            }
            dsum += __shfl_xor(dsum, 1, 64);
            if (!half) sZ[row] = 1.f / (dsum + 1e-6f);
        }
        __syncthreads();
        // o1 = q_h @ kv_h^T  (wave computes 64 rows x 32 m-cols)
        f32x4 acco[4][2];
        #pragma unroll
        for (int f = 0; f < 4; f++)
            #pragma unroll
            for (int j = 0; j < 2; j++) acco[f][j] = (f32x4){0.f, 0.f, 0.f, 0.f};
        #pragma unroll
        for (int ko = 0; ko < 64; ko += 32) {
            bf16x8 af[4], bfr[2];
            int pg = ((quad + (ko >> 3)) ^ (l16 & 7)) << 3;
            #pragma unroll
            for (int f = 0; f < 4; f++)
                af[f] = *(const bf16x8*)&sQ[(wm * 64 + f * 16 + l16) * 64 + pg];
            #pragma unroll
            for (int j = 0; j < 2; j++)
                bfr[j] = *(const bf16x8*)&sKV[(wn * 32 + j * 16 + l16) * 64 + pg];
            #pragma unroll
            for (int f = 0; f < 4; f++)
                #pragma unroll
                for (int j = 0; j < 2; j++)
                    acco[f][j] = __builtin_amdgcn_mfma_f32_16x16x32_bf16(af[f], bfr[j], acco[f][j], 0, 0, 0);
        }
        // scale by z, write to sO1 (swizzled A-layout)
        #pragma unroll
        for (int f = 0; f < 4; f++)
            #pragma unroll
            for (int j = 0; j < 2; j++)
                #pragma unroll
                for (int r = 0; r < 4; r++) {
                    int row = wm * 64 + f * 16 + quad * 4 + r;
                    int col = wn * 32 + j * 16 + l16;
                    float v = acco[f][j][r] * sZ[row];
                    int grp = col >> 3;
                    sO1[row * 64 + ((grp ^ (row & 7)) << 3) + (col & 7)] = f2b(v);
                }
        __syncthreads();
        // accumulate o1_h @ Wo_h for both ntiles (af shared)
        #pragma unroll
        for (int ko = 0; ko < 64; ko += 32) {
            bf16x8 af[4], bfr0[4], bfr1[4];
            int pg = ((quad + (ko >> 3)) ^ (l16 & 7)) << 3;
            #pragma unroll
            for (int f = 0; f < 4; f++)
                af[f] = *(const bf16x8*)&sO1[(wm * 64 + f * 16 + l16) * 64 + pg];
            #pragma unroll
            for (int f = 0; f < 4; f++) {
                bfr0[f] = *(const bf16x8*)&sWo[0][(wn * 64 + f * 16 + l16) * 64 + pg];
                bfr1[f] = *(const bf16x8*)&sWo[1][(wn * 64 + f * 16 + l16) * 64 + pg];
            }
            #pragma unroll
            for (int i = 0; i < 4; i++)
                #pragma unroll
                for (int j = 0; j < 4; j++) {
                    accm[0][i][j] = __builtin_amdgcn_mfma_f32_16x16x32_bf16(af[i], bfr0[j], accm[0][i][j], 0, 0, 0);
                    accm[1][i][j] = __builtin_amdgcn_mfma_f32_16x16x32_bf16(af[i], bfr1[j], accm[1][i][j], 0, 0, 0);
                }
        }
        __syncthreads();
    }
    #pragma unroll
    for (int n = 0; n < 2; n++)
        #pragma unroll
        for (int i = 0; i < 4; i++)
            #pragma unroll
            for (int j = 0; j < 4; j++) {
                int gcol = nbase + n * 128 + wn * 64 + j * 16 + l16;
                float bv = bo[gcol];
                #pragma unroll
                for (int r = 0; r < 4; r++) {
                    int grow = mbase + wm * 64 + i * 16 + quad * 4 + r;
                    out[(size_t)grow * 512 + gcol] = accm[n][i][j][r] + bv;
                }
            }
}

// ---------------- launch -----------------------------------------------------
extern "C" void kernel_launch(void* const* d_in, const int* in_sizes, int n_in,
                              void* d_out, int out_size, void* d_ws, size_t ws_size,
                              hipStream_t stream) {
    const float* x  = (const float*)d_in[0];
    const float* Wq = (const float*)d_in[1];
    const float* bq = (const float*)d_in[2];
    const float* Wk = (const float*)d_in[3];
    const float* bk = (const float*)d_in[4];
    const float* Wv = (const float*)d_in[5];
    const float* bv = (const float*)d_in[6];
    const float* Wo = (const float*)d_in[7];
    const float* bo = (const float*)d_in[8];
    float* out = (float*)d_out;

    char* wsb = (char*)d_ws;
    char* ob  = (char*)d_out;
    // d_out scratch (dead before fused_out writes):
    unsigned short* vT  = (unsigned short*)ob;                    // 32 MB
    unsigned short* xb  = (unsigned short*)(ob + 33554432ull);    // 32 MB, dead after gemm_qkv
    // ws:
    unsigned short* qb  = (unsigned short*)wsb;                   // 32 MB
    unsigned short* kT  = (unsigned short*)(wsb + 33554432ull);   // 32 MB
    unsigned short* wt  = (unsigned short*)(wsb + 67108864ull);   // 2 MB
    float*          kvg = (float*)(wsb + 69206016ull);            // 1 MB
    float*          ksg = (float*)(wsb + 70254592ull);            // 16 KB

    prep_kernel<<<16640, 256, 0, stream>>>(x, Wq, Wk, Wv, Wo, xb, wt, ksg, kvg);
    gemm_qkv_kernel<<<3072, 256, 0, stream>>>(xb, wt, bq, bk, bv, qb, kT, vT, ksg);
    kv_kernel<<<512, 256, 0, stream>>>(kT, vT, kvg);
    fused_out_kernel<<<512, 256, 0, stream>>>(qb, kvg, ksg,
            wt + 3ull * 512 * 512, bo, out);
}